// Round 6
// baseline (287.858 us; speedup 1.0000x reference)
//
#include <hip/hip_runtime.h>
#include <stdint.h>

// Problem constants
#define CC 8
#define NN 1024
#define CN 8192
#define NE 65536
#define NEG_SLOPE 0.2f

typedef __attribute__((ext_vector_type(8))) short bf16x8;
typedef __attribute__((ext_vector_type(4))) float f32x4;

__device__ __forceinline__ ushort f2bfu(float x) {
    unsigned u = __float_as_uint(x);
    unsigned r = u + 0x7fffu + ((u >> 16) & 1u);
    return (ushort)(r >> 16);
}

// ---------------- masks scatter ----------------
__global__ void k_scatter(const int* __restrict__ edges,
                          float* __restrict__ msrc, float* __restrict__ mdst) {
    int e = blockIdx.x * 256 + threadIdx.x;
    if (e < NE) {
        msrc[edges[e]] = 1.0f;
        mdst[edges[NE + e]] = 1.0f;
    }
}

// ---------------- per-type linear: feat[c][t][n][k] = hs[cn,t,:] @ fc[t,:,:] (f32) ----------------
// grid (512, 3): bx&1 = k-half (128 cols), bx>>1 = 32-row block. block 256.
__global__ void __launch_bounds__(256) k_feat(const float* __restrict__ nf,
                                              const float* __restrict__ fc,
                                              float* __restrict__ feat) {
    __shared__ float sFC[64][132];        // fc[i][k-half] f32, padded
    __shared__ float sHT[64][36];         // transposed hs: [i][r] f32
    int t = threadIdx.x;
    int tt = blockIdx.y;
    int kh = blockIdx.x & 1;
    int r0 = (blockIdx.x >> 1) * 32;
    {   // load fc half-plane: 64 x 128 f32
        const float* fcp = fc + tt * 16384 + kh * 128;
        #pragma unroll
        for (int i = 0; i < 8; ++i) {
            int f4 = t + 256 * i;
            int row = f4 >> 5, c4 = f4 & 31;
            *(float4*)&sFC[row][c4 * 4] = *(const float4*)(fcp + row * 256 + c4 * 4);
        }
    }
    {   // load 32 rows x 64 inputs, transpose into sHT
        #pragma unroll
        for (int i = 0; i < 2; ++i) {
            int f4 = t + 256 * i;
            int r = f4 >> 4, c4 = f4 & 15;
            float4 v = *(const float4*)(nf + (size_t)(r0 + r) * 192 + tt * 64 + c4 * 4);
            sHT[c4 * 4 + 0][r] = v.x;
            sHT[c4 * 4 + 1][r] = v.y;
            sHT[c4 * 4 + 2][r] = v.z;
            sHT[c4 * 4 + 3][r] = v.w;
        }
    }
    __syncthreads();
    int rg = t >> 5;        // rows rg*4..+4
    int kg = t & 31;        // cols kg*4..+4 (of this 128 half)
    float acc[4][4];
    #pragma unroll
    for (int a = 0; a < 4; ++a)
        #pragma unroll
        for (int b = 0; b < 4; ++b) acc[a][b] = 0.f;
    #pragma unroll 4
    for (int i = 0; i < 64; ++i) {
        float4 hv = *(const float4*)&sHT[i][rg * 4];
        float4 fv = *(const float4*)&sFC[i][kg * 4];
        const float* fp = (const float*)&fv;
        #pragma unroll
        for (int b = 0; b < 4; ++b) {
            acc[0][b] += hv.x * fp[b];
            acc[1][b] += hv.y * fp[b];
            acc[2][b] += hv.z * fp[b];
            acc[3][b] += hv.w * fp[b];
        }
    }
    #pragma unroll
    for (int a = 0; a < 4; ++a) {
        int b = r0 + rg * 4 + a;
        int c = b >> 10, n = b & 1023;
        float4 vv = {acc[a][0], acc[a][1], acc[a][2], acc[a][3]};
        *(float4*)(feat + (size_t)c * 786432 + (size_t)tt * 262144 + n * 256 + kh * 128 + kg * 4) = vv;
    }
}

// ---------------- fused remap + transpose: feat -> fdt (bf16, masked) + attention partials ----------------
// grid (16 u-tiles, 3 t2, 8 c), block 256.  thread t: nl = t>>2 (node 0..63), q = t&3 (= h).
// feat is read in the reference's reinterpreted order: linear [c][t2][n][k] read as
// [c][n][t2][h][f] -> index c*786432 + n*768 + t2*256 + h*64 + f.
// Each thread owns the FULL 64-f slice of (node, h): attention partial = plain dot, no
// cross-lane reduce; 2 atomicAdds per thread (a_src/a_dst zeroed by host memset).
// Transpose via LDS: row (q*64+f), col nl; row stride 88 ushorts + q*16 skew ->
// conflict-free phase-1 writes.
__global__ void __launch_bounds__(256) k_rt(const float* __restrict__ feat,
                        const float* __restrict__ attn_src, const float* __restrict__ attn_dst,
                        const float* __restrict__ msrc, const float* __restrict__ mdst,
                        ushort* __restrict__ fdt, float* __restrict__ a_src, float* __restrict__ a_dst) {
    __shared__ ushort T[22560];           // 256 rows x 88 + skew, 45.1 KB
    int u0 = blockIdx.x * 64;
    int t2 = blockIdx.y;
    int c  = blockIdx.z;
    int t = threadIdx.x;
    int nl = t >> 2, q = t & 3;
    int b = (c << 10) + u0 + nl;
    float md = mdst[b], ms = msrc[b];
    const float* fp  = feat + (size_t)c * 786432 + (size_t)(u0 + nl) * 768 + t2 * 256 + q * 64;
    const float* wsp = attn_src + q * 192 + t2 * 64;
    const float* wdp = attn_dst + q * 192 + t2 * 64;
    float ssum = 0.f, dsum = 0.f;
    #pragma unroll
    for (int i4 = 0; i4 < 16; ++i4) {
        float4 v = *(const float4*)(fp + i4 * 4);
        const float* vv = (const float*)&v;
        #pragma unroll
        for (int k = 0; k < 4; ++k) {
            int f = i4 * 4 + k;
            ssum += vv[k] * wsp[f];
            dsum += vv[k] * wdp[f];
            T[(q * 64 + f) * 88 + q * 16 + nl] = f2bfu(vv[k] * md);
        }
    }
    atomicAdd(&a_src[(b << 2) + q], ssum * ms);
    atomicAdd(&a_dst[(b << 2) + q], dsum * md);
    __syncthreads();
    // phase 2: one fdt row (128 B) per thread.  row = (c*4+h2)*192 + t2*64 + j, cols u0..u0+63
    int h2 = t >> 6, j = t & 63;
    const ushort* row = &T[(h2 * 64 + j) * 88 + h2 * 16];
    ushort* dst = fdt + (size_t)((c * 4 + h2) * 192 + t2 * 64 + j) * 1024 + u0;
    #pragma unroll
    for (int i = 0; i < 8; ++i)
        *(uint4*)(dst + i * 8) = *(const uint4*)(row + i * 8);
}

// ---------------- attention + softmax over c; writes a (f32, d_out) and Abuf[ch][v][u] bf16 ----------------
// grid (1024 v, 2 u-chunks), block 256; thread handles u0 = chunk*512 + t*2 and u0+1
// 3-pass recompute softmax: no per-thread logit array -> no scratch spill.
__global__ void __launch_bounds__(256) k_att(const float* __restrict__ a_src,
                                             const float* __restrict__ a_dst,
                                             float* __restrict__ a_out, ushort* __restrict__ Abuf) {
    __shared__ float sAS[32];
    int v = blockIdx.x;
    int t = threadIdx.x;
    if (t < 32) sAS[t] = a_src[((t >> 2) * 1024 + v) * 4 + (t & 3)];
    __syncthreads();
    int u0 = blockIdx.y * 512 + t * 2;

    // ---- pass 1: raw max over c (leaky/clip applied once afterwards) ----
    float mx0[4], mx1[4];
    #pragma unroll
    for (int h = 0; h < 4; ++h) { mx0[h] = -1e30f; mx1[h] = -1e30f; }
    #pragma unroll
    for (int c = 0; c < 8; ++c) {
        float4 d0 = *(const float4*)(a_dst + ((c << 10) + u0) * 4);
        float4 d1 = *(const float4*)(a_dst + ((c << 10) + u0 + 1) * 4);
        const float* dp0 = (const float*)&d0;
        const float* dp1 = (const float*)&d1;
        #pragma unroll
        for (int h = 0; h < 4; ++h) {
            float as = sAS[c * 4 + h];
            mx0[h] = fmaxf(mx0[h], as + dp0[h]);
            mx1[h] = fmaxf(mx1[h], as + dp1[h]);
        }
    }
    #pragma unroll
    for (int h = 0; h < 4; ++h) {
        float x = mx0[h];
        x = (x >= 0.f) ? x : NEG_SLOPE * x;
        mx0[h] = fminf(fmaxf(x, -1e9f), 1e9f);
        float y = mx1[h];
        y = (y >= 0.f) ? y : NEG_SLOPE * y;
        mx1[h] = fminf(fmaxf(y, -1e9f), 1e9f);
    }

    // ---- pass 2: recompute logits, accumulate exp sums ----
    float s0[4] = {0.f, 0.f, 0.f, 0.f}, s1[4] = {0.f, 0.f, 0.f, 0.f};
    #pragma unroll
    for (int c = 0; c < 8; ++c) {
        float4 d0 = *(const float4*)(a_dst + ((c << 10) + u0) * 4);
        float4 d1 = *(const float4*)(a_dst + ((c << 10) + u0 + 1) * 4);
        const float* dp0 = (const float*)&d0;
        const float* dp1 = (const float*)&d1;
        #pragma unroll
        for (int h = 0; h < 4; ++h) {
            float as = sAS[c * 4 + h];
            float x = as + dp0[h];
            x = (x >= 0.f) ? x : NEG_SLOPE * x;
            x = fminf(fmaxf(x, -1e9f), 1e9f);
            s0[h] += __expf(x - mx0[h]);
            float y = as + dp1[h];
            y = (y >= 0.f) ? y : NEG_SLOPE * y;
            y = fminf(fmaxf(y, -1e9f), 1e9f);
            s1[h] += __expf(y - mx1[h]);
        }
    }
    float r0[4], r1[4];
    #pragma unroll
    for (int h = 0; h < 4; ++h) { r0[h] = 1.f / s0[h]; r1[h] = 1.f / s1[h]; }

    // ---- pass 3: recompute, normalize, write a_out (f32) + Abuf (bf16) ----
    #pragma unroll
    for (int c = 0; c < 8; ++c) {
        float4 d0 = *(const float4*)(a_dst + ((c << 10) + u0) * 4);
        float4 d1 = *(const float4*)(a_dst + ((c << 10) + u0 + 1) * 4);
        const float* dp0 = (const float*)&d0;
        const float* dp1 = (const float*)&d1;
        float w0[4], w1[4];
        unsigned packs[4];
        #pragma unroll
        for (int h = 0; h < 4; ++h) {
            float as = sAS[c * 4 + h];
            float x = as + dp0[h];
            x = (x >= 0.f) ? x : NEG_SLOPE * x;
            x = fminf(fmaxf(x, -1e9f), 1e9f);
            float p0 = __expf(x - mx0[h]) * r0[h];
            float y = as + dp1[h];
            y = (y >= 0.f) ? y : NEG_SLOPE * y;
            y = fminf(fmaxf(y, -1e9f), 1e9f);
            float p1 = __expf(y - mx1[h]) * r1[h];
            w0[h] = p0; w1[h] = p1;
            packs[h] = (unsigned)f2bfu(p0) | ((unsigned)f2bfu(p1) << 16);
        }
        float* ao = a_out + ((size_t)((c << 10) + v) * 1024 + u0) * 4;
        *(float4*)ao = *(const float4*)w0;
        *((float4*)ao + 1) = *(const float4*)w1;
        #pragma unroll
        for (int h = 0; h < 4; ++h)
            *(unsigned*)(Abuf + (size_t)((c * 4 + h) * 1024 + v) * 1024 + u0) = packs[h];
    }
}

// ---------------- GEMM per (c,h): M[v][j] = sum_u A[v][u] * fdt[j][u] ----------------
// grid (16 v-tiles, 32 ch) = 512 blocks, block 256 (4 waves). BM=64, BN=192, BK=64.
// 2 blocks/CU -> 8 waves/CU: staging latency of one block hides under the other's MFMA.
// Waves split N: wave wid covers cols wid*48..+48 (3x16), full 64 rows (4x16).
__global__ void __launch_bounds__(256) k_gemm(const ushort* __restrict__ A,
                                              const ushort* __restrict__ B,
                                              float* __restrict__ Mout) {
    __shared__ ushort sA[64 * 72];
    __shared__ ushort sB[192 * 72];
    int ch = blockIdx.y;
    int v0 = blockIdx.x * 64;
    int t = threadIdx.x;
    const ushort* pA = A + (size_t)ch * (1024 * 1024) + (size_t)v0 * 1024;
    const ushort* pB = B + (size_t)ch * (192 * 1024);
    int wid = t >> 6, lane = t & 63;
    int wn = wid * 48;
    int lm = lane & 15, lq = lane >> 4;
    f32x4 acc[4][3];
    #pragma unroll
    for (int i = 0; i < 4; ++i)
        #pragma unroll
        for (int j = 0; j < 3; ++j)
            acc[i][j] = (f32x4){0.f, 0.f, 0.f, 0.f};
    for (int kk = 0; kk < 1024; kk += 64) {
        #pragma unroll
        for (int i = 0; i < 2; ++i) {
            int cid = t + 256 * i;
            int r = cid >> 3, kc = cid & 7;
            uint4 vv = *(const uint4*)(pA + (size_t)r * 1024 + kk + kc * 8);
            *(uint4*)&sA[r * 72 + kc * 8] = vv;
        }
        #pragma unroll
        for (int i = 0; i < 6; ++i) {
            int cid = t + 256 * i;
            int r = cid >> 3, kc = cid & 7;
            uint4 vv = *(const uint4*)(pB + (size_t)r * 1024 + kk + kc * 8);
            *(uint4*)&sB[r * 72 + kc * 8] = vv;
        }
        __syncthreads();
        #pragma unroll
        for (int ks = 0; ks < 64; ks += 32) {
            bf16x8 af[4], bg[3];
            #pragma unroll
            for (int i = 0; i < 4; ++i)
                af[i] = *(const bf16x8*)&sA[(i * 16 + lm) * 72 + ks + lq * 8];
            #pragma unroll
            for (int j = 0; j < 3; ++j)
                bg[j] = *(const bf16x8*)&sB[(wn + j * 16 + lm) * 72 + ks + lq * 8];
            #pragma unroll
            for (int i = 0; i < 4; ++i)
                #pragma unroll
                for (int j = 0; j < 3; ++j)
                    acc[i][j] = __builtin_amdgcn_mfma_f32_16x16x32_bf16(af[i], bg[j], acc[i][j], 0, 0, 0);
        }
        __syncthreads();
    }
    float* pM = Mout + (size_t)ch * 196608 + (size_t)v0 * 192;
    #pragma unroll
    for (int i = 0; i < 4; ++i)
        #pragma unroll
        for (int r = 0; r < 4; ++r) {
            int row = i * 16 + lq * 4 + r;
            #pragma unroll
            for (int j = 0; j < 3; ++j)
                pM[(size_t)row * 192 + wn + j * 16 + lm] = acc[i][j][r];
        }
}

// ---------------- epilogue: outs[c][v][tf] = sum_h relu(M[ch][v][tf]) (f32) ----------------
__global__ void k_out(const float* __restrict__ Mm, float* __restrict__ outp) {
    int b = blockIdx.x;
    int c = b >> 10, v = b & 1023;
    int tf = threadIdx.x;
    float s = 0.f;
    #pragma unroll
    for (int h = 0; h < 4; ++h) {
        float x = Mm[(size_t)(c * 4 + h) * 196608 + (size_t)v * 192 + tf];
        s += fmaxf(x, 0.f);
    }
    outp[(size_t)b * 192 + tf] = s;
}

extern "C" void kernel_launch(void* const* d_in, const int* in_sizes, int n_in,
                              void* d_out, int out_size, void* d_ws, size_t ws_size,
                              hipStream_t stream) {
    const int*   edges  = (const int*)d_in[0];
    const float* nf     = (const float*)d_in[1];
    const float* fc     = (const float*)d_in[2];
    const float* asrc_w = (const float*)d_in[3];
    const float* adst_w = (const float*)d_in[4];
    float* outp  = (float*)d_out;
    float* a_out = outp + 1572864;     // outs (1,572,864 f32) then a (33,554,432 f32)

    char* ws = (char*)d_ws;
    float*  msrc  = (float*)(ws + 0);            // 32 KB
    float*  mdst  = (float*)(ws + 32768);        // 32 KB
    float*  a_src = (float*)(ws + 65536);        // 128 KB (atomic-accumulated)
    float*  a_dst = (float*)(ws + 196608);       // 128 KB (atomic-accumulated)
    ushort* fdt   = (ushort*)(ws + 327680);      // 12.58 MB bf16
    float*  feat  = (float*)(ws + 12910592);     // 25.17 MB f32 (aliased with Mm)
    float*  Mm    = feat;                        // feat dead after k_rt
    ushort* Abuf  = (ushort*)(ws + 38076416);    // 67.1 MB bf16

    hipMemsetAsync(msrc, 0, 327680, stream);     // zero masks + a_src + a_dst
    k_scatter<<<dim3(256), dim3(256), 0, stream>>>(edges, msrc, mdst);
    k_feat<<<dim3(512, 3), dim3(256), 0, stream>>>(nf, fc, feat);
    k_rt<<<dim3(16, 3, 8), dim3(256), 0, stream>>>(feat, asrc_w, adst_w, msrc, mdst, fdt, a_src, a_dst);
    k_att<<<dim3(1024, 2), dim3(256), 0, stream>>>(a_src, a_dst, a_out, Abuf);
    k_gemm<<<dim3(16, 32), dim3(256), 0, stream>>>(Abuf, fdt, Mm);
    k_out<<<dim3(8192), dim3(192), 0, stream>>>(Mm, outp);
}

// Round 9
// 254.876 us; speedup vs baseline: 1.1294x; 1.1294x over previous
//
#include <hip/hip_runtime.h>
#include <stdint.h>

// Problem constants
#define CC 8
#define NN 1024
#define CN 8192
#define NE 65536
#define NEG_SLOPE 0.2f

typedef __attribute__((ext_vector_type(8))) short bf16x8;
typedef __attribute__((ext_vector_type(4))) float f32x4;

__device__ __forceinline__ ushort f2bfu(float x) {
    unsigned u = __float_as_uint(x);
    unsigned r = u + 0x7fffu + ((u >> 16) & 1u);
    return (ushort)(r >> 16);
}

// ---------------- masks scatter ----------------
__global__ void k_scatter(const int* __restrict__ edges,
                          float* __restrict__ msrc, float* __restrict__ mdst) {
    int e = blockIdx.x * 256 + threadIdx.x;
    if (e < NE) {
        msrc[edges[e]] = 1.0f;
        mdst[edges[NE + e]] = 1.0f;
    }
}

// ---------------- per-type linear: feat[c][t][n][k] = hs[cn,t,:] @ fc[t,:,:] (f32) ----------------
// grid (512, 3): bx&1 = k-half (128 cols), bx>>1 = 32-row block. block 256.
__global__ void __launch_bounds__(256) k_feat(const float* __restrict__ nf,
                                              const float* __restrict__ fc,
                                              float* __restrict__ feat) {
    __shared__ float sFC[64][132];        // fc[i][k-half] f32, padded
    __shared__ float sHT[64][36];         // transposed hs: [i][r] f32
    int t = threadIdx.x;
    int tt = blockIdx.y;
    int kh = blockIdx.x & 1;
    int r0 = (blockIdx.x >> 1) * 32;
    {   // load fc half-plane: 64 x 128 f32
        const float* fcp = fc + tt * 16384 + kh * 128;
        #pragma unroll
        for (int i = 0; i < 8; ++i) {
            int f4 = t + 256 * i;
            int row = f4 >> 5, c4 = f4 & 31;
            *(float4*)&sFC[row][c4 * 4] = *(const float4*)(fcp + row * 256 + c4 * 4);
        }
    }
    {   // load 32 rows x 64 inputs, transpose into sHT
        #pragma unroll
        for (int i = 0; i < 2; ++i) {
            int f4 = t + 256 * i;
            int r = f4 >> 4, c4 = f4 & 15;
            float4 v = *(const float4*)(nf + (size_t)(r0 + r) * 192 + tt * 64 + c4 * 4);
            sHT[c4 * 4 + 0][r] = v.x;
            sHT[c4 * 4 + 1][r] = v.y;
            sHT[c4 * 4 + 2][r] = v.z;
            sHT[c4 * 4 + 3][r] = v.w;
        }
    }
    __syncthreads();
    int rg = t >> 5;        // rows rg*4..+4
    int kg = t & 31;        // cols kg*4..+4 (of this 128 half)
    float acc[4][4];
    #pragma unroll
    for (int a = 0; a < 4; ++a)
        #pragma unroll
        for (int b = 0; b < 4; ++b) acc[a][b] = 0.f;
    #pragma unroll 4
    for (int i = 0; i < 64; ++i) {
        float4 hv = *(const float4*)&sHT[i][rg * 4];
        float4 fv = *(const float4*)&sFC[i][kg * 4];
        const float* fp = (const float*)&fv;
        #pragma unroll
        for (int b = 0; b < 4; ++b) {
            acc[0][b] += hv.x * fp[b];
            acc[1][b] += hv.y * fp[b];
            acc[2][b] += hv.z * fp[b];
            acc[3][b] += hv.w * fp[b];
        }
    }
    #pragma unroll
    for (int a = 0; a < 4; ++a) {
        int b = r0 + rg * 4 + a;
        int c = b >> 10, n = b & 1023;
        float4 vv = {acc[a][0], acc[a][1], acc[a][2], acc[a][3]};
        *(float4*)(feat + (size_t)c * 786432 + (size_t)tt * 262144 + n * 256 + kh * 128 + kg * 4) = vv;
    }
}

// ---------------- fused remap + transpose: feat -> fdt (bf16, masked) + attention partials ----------------
// grid (16 u-tiles, 3 t2, 8 c), block 256.  thread t: nl = t>>2 (node 0..63), q = t&3 (= h).
__global__ void __launch_bounds__(256) k_rt(const float* __restrict__ feat,
                        const float* __restrict__ attn_src, const float* __restrict__ attn_dst,
                        const float* __restrict__ msrc, const float* __restrict__ mdst,
                        ushort* __restrict__ fdt, float* __restrict__ a_src, float* __restrict__ a_dst) {
    __shared__ ushort T[22560];           // 256 rows x 88 + skew, 45.1 KB
    int u0 = blockIdx.x * 64;
    int t2 = blockIdx.y;
    int c  = blockIdx.z;
    int t = threadIdx.x;
    int nl = t >> 2, q = t & 3;
    int b = (c << 10) + u0 + nl;
    float md = mdst[b], ms = msrc[b];
    const float* fp  = feat + (size_t)c * 786432 + (size_t)(u0 + nl) * 768 + t2 * 256 + q * 64;
    const float* wsp = attn_src + q * 192 + t2 * 64;
    const float* wdp = attn_dst + q * 192 + t2 * 64;
    float ssum = 0.f, dsum = 0.f;
    #pragma unroll
    for (int i4 = 0; i4 < 16; ++i4) {
        float4 v = *(const float4*)(fp + i4 * 4);
        const float* vv = (const float*)&v;
        #pragma unroll
        for (int k = 0; k < 4; ++k) {
            int f = i4 * 4 + k;
            ssum += vv[k] * wsp[f];
            dsum += vv[k] * wdp[f];
            T[(q * 64 + f) * 88 + q * 16 + nl] = f2bfu(vv[k] * md);
        }
    }
    atomicAdd(&a_src[(b << 2) + q], ssum * ms);
    atomicAdd(&a_dst[(b << 2) + q], dsum * md);
    __syncthreads();
    // phase 2: one fdt row (128 B) per thread.
    int h2 = t >> 6, j = t & 63;
    const ushort* row = &T[(h2 * 64 + j) * 88 + h2 * 16];
    ushort* dst = fdt + (size_t)((c * 4 + h2) * 192 + t2 * 64 + j) * 1024 + u0;
    #pragma unroll
    for (int i = 0; i < 8; ++i)
        *(uint4*)(dst + i * 8) = *(const uint4*)(row + i * 8);
}

// ---------------- attention + softmax over c ----------------
// grid (1024 v, 2 u-chunks), block 256; thread handles u0 = chunk*512 + t and u1 = u0 + 256.
// Dense lane mapping: EVERY load/store instruction is gap-free across the wave
// (a_out float4: lane stride 16B; Abuf ushort: lane stride 2B).
// 3-pass recompute softmax: no per-thread logit array -> no scratch spill.
__global__ void __launch_bounds__(256) k_att(const float* __restrict__ a_src,
                                             const float* __restrict__ a_dst,
                                             float* __restrict__ a_out, ushort* __restrict__ Abuf) {
    __shared__ float sAS[32];
    int v = blockIdx.x;
    int t = threadIdx.x;
    if (t < 32) sAS[t] = a_src[((t >> 2) * 1024 + v) * 4 + (t & 3)];
    __syncthreads();
    int u0 = blockIdx.y * 512 + t;
    int u1 = u0 + 256;

    // ---- pass 1: raw max over c (leaky/clip applied once afterwards) ----
    float mx0[4], mx1[4];
    #pragma unroll
    for (int h = 0; h < 4; ++h) { mx0[h] = -1e30f; mx1[h] = -1e30f; }
    #pragma unroll
    for (int c = 0; c < 8; ++c) {
        float4 d0 = *(const float4*)(a_dst + ((c << 10) + u0) * 4);
        float4 d1 = *(const float4*)(a_dst + ((c << 10) + u1) * 4);
        const float* dp0 = (const float*)&d0;
        const float* dp1 = (const float*)&d1;
        #pragma unroll
        for (int h = 0; h < 4; ++h) {
            float as = sAS[c * 4 + h];
            mx0[h] = fmaxf(mx0[h], as + dp0[h]);
            mx1[h] = fmaxf(mx1[h], as + dp1[h]);
        }
    }
    #pragma unroll
    for (int h = 0; h < 4; ++h) {
        float x = mx0[h];
        x = (x >= 0.f) ? x : NEG_SLOPE * x;
        mx0[h] = fminf(fmaxf(x, -1e9f), 1e9f);
        float y = mx1[h];
        y = (y >= 0.f) ? y : NEG_SLOPE * y;
        mx1[h] = fminf(fmaxf(y, -1e9f), 1e9f);
    }

    // ---- pass 2: recompute logits, accumulate exp sums ----
    float s0[4] = {0.f, 0.f, 0.f, 0.f}, s1[4] = {0.f, 0.f, 0.f, 0.f};
    #pragma unroll
    for (int c = 0; c < 8; ++c) {
        float4 d0 = *(const float4*)(a_dst + ((c << 10) + u0) * 4);
        float4 d1 = *(const float4*)(a_dst + ((c << 10) + u1) * 4);
        const float* dp0 = (const float*)&d0;
        const float* dp1 = (const float*)&d1;
        #pragma unroll
        for (int h = 0; h < 4; ++h) {
            float as = sAS[c * 4 + h];
            float x = as + dp0[h];
            x = (x >= 0.f) ? x : NEG_SLOPE * x;
            x = fminf(fmaxf(x, -1e9f), 1e9f);
            s0[h] += __expf(x - mx0[h]);
            float y = as + dp1[h];
            y = (y >= 0.f) ? y : NEG_SLOPE * y;
            y = fminf(fmaxf(y, -1e9f), 1e9f);
            s1[h] += __expf(y - mx1[h]);
        }
    }
    float r0[4], r1[4];
    #pragma unroll
    for (int h = 0; h < 4; ++h) { r0[h] = 1.f / s0[h]; r1[h] = 1.f / s1[h]; }

    // ---- pass 3: recompute, normalize, write a_out (f32) + Abuf (bf16) ----
    #pragma unroll
    for (int c = 0; c < 8; ++c) {
        float4 d0 = *(const float4*)(a_dst + ((c << 10) + u0) * 4);
        float4 d1 = *(const float4*)(a_dst + ((c << 10) + u1) * 4);
        const float* dp0 = (const float*)&d0;
        const float* dp1 = (const float*)&d1;
        float w0[4], w1[4];
        #pragma unroll
        for (int h = 0; h < 4; ++h) {
            float as = sAS[c * 4 + h];
            float x = as + dp0[h];
            x = (x >= 0.f) ? x : NEG_SLOPE * x;
            x = fminf(fmaxf(x, -1e9f), 1e9f);
            w0[h] = __expf(x - mx0[h]) * r0[h];
            float y = as + dp1[h];
            y = (y >= 0.f) ? y : NEG_SLOPE * y;
            y = fminf(fmaxf(y, -1e9f), 1e9f);
            w1[h] = __expf(y - mx1[h]) * r1[h];
        }
        float* ao0 = a_out + ((size_t)((c << 10) + v) * 1024 + u0) * 4;
        float* ao1 = a_out + ((size_t)((c << 10) + v) * 1024 + u1) * 4;
        *(float4*)ao0 = *(const float4*)w0;
        *(float4*)ao1 = *(const float4*)w1;
        #pragma unroll
        for (int h = 0; h < 4; ++h) {
            ushort* ab = Abuf + (size_t)((c * 4 + h) * 1024 + v) * 1024;
            ab[u0] = f2bfu(w0[h]);
            ab[u1] = f2bfu(w1[h]);
        }
    }
}

// ---------------- GEMM per (c,h): M[v][j] = sum_u A[v][u] * fdt[j][u] ----------------
// grid (8 v-tiles, 32 ch) = 256 blocks, block 512 (8 waves). BM=128, BN=192, BK=64.
// Halved B-panel replication vs BM=64 (staged bytes 268 -> 165 MB); 8 waves/CU.
// Wave grid 2m x 4n: wave covers 64 rows (4x16) x 48 cols (3x16).
__global__ void __launch_bounds__(512) k_gemm(const ushort* __restrict__ A,
                                              const ushort* __restrict__ B,
                                              float* __restrict__ Mout) {
    __shared__ ushort sA[128 * 72];
    __shared__ ushort sB[192 * 72];
    int ch = blockIdx.y;
    int v0 = blockIdx.x * 128;
    int t = threadIdx.x;
    const ushort* pA = A + (size_t)ch * (1024 * 1024) + (size_t)v0 * 1024;
    const ushort* pB = B + (size_t)ch * (192 * 1024);
    int wid = t >> 6, lane = t & 63;
    int wm = (wid >> 2) * 64, wn = (wid & 3) * 48;
    int lm = lane & 15, lq = lane >> 4;
    f32x4 acc[4][3];
    #pragma unroll
    for (int i = 0; i < 4; ++i)
        #pragma unroll
        for (int j = 0; j < 3; ++j)
            acc[i][j] = (f32x4){0.f, 0.f, 0.f, 0.f};
    for (int kk = 0; kk < 1024; kk += 64) {
        #pragma unroll
        for (int i = 0; i < 2; ++i) {
            int cid = t + 512 * i;
            int r = cid >> 3, kc = cid & 7;
            uint4 vv = *(const uint4*)(pA + (size_t)r * 1024 + kk + kc * 8);
            *(uint4*)&sA[r * 72 + kc * 8] = vv;
        }
        #pragma unroll
        for (int i = 0; i < 3; ++i) {
            int cid = t + 512 * i;
            int r = cid >> 3, kc = cid & 7;
            uint4 vv = *(const uint4*)(pB + (size_t)r * 1024 + kk + kc * 8);
            *(uint4*)&sB[r * 72 + kc * 8] = vv;
        }
        __syncthreads();
        #pragma unroll
        for (int ks = 0; ks < 64; ks += 32) {
            bf16x8 af[4], bg[3];
            #pragma unroll
            for (int i = 0; i < 4; ++i)
                af[i] = *(const bf16x8*)&sA[(wm + i * 16 + lm) * 72 + ks + lq * 8];
            #pragma unroll
            for (int j = 0; j < 3; ++j)
                bg[j] = *(const bf16x8*)&sB[(wn + j * 16 + lm) * 72 + ks + lq * 8];
            #pragma unroll
            for (int i = 0; i < 4; ++i)
                #pragma unroll
                for (int j = 0; j < 3; ++j)
                    acc[i][j] = __builtin_amdgcn_mfma_f32_16x16x32_bf16(af[i], bg[j], acc[i][j], 0, 0, 0);
        }
        __syncthreads();
    }
    float* pM = Mout + (size_t)ch * 196608 + (size_t)v0 * 192;
    #pragma unroll
    for (int i = 0; i < 4; ++i)
        #pragma unroll
        for (int r = 0; r < 4; ++r) {
            int row = wm + i * 16 + lq * 4 + r;
            #pragma unroll
            for (int j = 0; j < 3; ++j)
                pM[(size_t)row * 192 + wn + j * 16 + lm] = acc[i][j][r];
        }
}

// ---------------- epilogue: outs[c][v][tf] = sum_h relu(M[ch][v][tf]) (f32) ----------------
__global__ void k_out(const float* __restrict__ Mm, float* __restrict__ outp) {
    int b = blockIdx.x;
    int c = b >> 10, v = b & 1023;
    int tf = threadIdx.x;
    float s = 0.f;
    #pragma unroll
    for (int h = 0; h < 4; ++h) {
        float x = Mm[(size_t)(c * 4 + h) * 196608 + (size_t)v * 192 + tf];
        s += fmaxf(x, 0.f);
    }
    outp[(size_t)b * 192 + tf] = s;
}

extern "C" void kernel_launch(void* const* d_in, const int* in_sizes, int n_in,
                              void* d_out, int out_size, void* d_ws, size_t ws_size,
                              hipStream_t stream) {
    const int*   edges  = (const int*)d_in[0];
    const float* nf     = (const float*)d_in[1];
    const float* fc     = (const float*)d_in[2];
    const float* asrc_w = (const float*)d_in[3];
    const float* adst_w = (const float*)d_in[4];
    float* outp  = (float*)d_out;
    float* a_out = outp + 1572864;     // outs (1,572,864 f32) then a (33,554,432 f32)

    char* ws = (char*)d_ws;
    float*  msrc  = (float*)(ws + 0);            // 32 KB
    float*  mdst  = (float*)(ws + 32768);        // 32 KB
    float*  a_src = (float*)(ws + 65536);        // 128 KB (atomic-accumulated)
    float*  a_dst = (float*)(ws + 196608);       // 128 KB (atomic-accumulated)
    ushort* fdt   = (ushort*)(ws + 327680);      // 12.58 MB bf16
    float*  feat  = (float*)(ws + 12910592);     // 25.17 MB f32 (aliased with Mm)
    float*  Mm    = feat;                        // feat dead after k_rt
    ushort* Abuf  = (ushort*)(ws + 38076416);    // 67.1 MB bf16

    hipMemsetAsync(msrc, 0, 327680, stream);     // zero masks + a_src + a_dst
    k_scatter<<<dim3(256), dim3(256), 0, stream>>>(edges, msrc, mdst);
    k_feat<<<dim3(512, 3), dim3(256), 0, stream>>>(nf, fc, feat);
    k_rt<<<dim3(16, 3, 8), dim3(256), 0, stream>>>(feat, asrc_w, adst_w, msrc, mdst, fdt, a_src, a_dst);
    k_att<<<dim3(1024, 2), dim3(256), 0, stream>>>(a_src, a_dst, a_out, Abuf);
    k_gemm<<<dim3(8, 32), dim3(512), 0, stream>>>(Abuf, fdt, Mm);
    k_out<<<dim3(8192), dim3(192), 0, stream>>>(Mm, outp);
}

// Round 10
// 249.930 us; speedup vs baseline: 1.1518x; 1.0198x over previous
//
#include <hip/hip_runtime.h>
#include <stdint.h>

// Problem constants
#define CC 8
#define NN 1024
#define CN 8192
#define NE 65536
#define NEG_SLOPE 0.2f

typedef __attribute__((ext_vector_type(8))) short bf16x8;
typedef __attribute__((ext_vector_type(4))) float f32x4;

__device__ __forceinline__ ushort f2bfu(float x) {
    unsigned u = __float_as_uint(x);
    unsigned r = u + 0x7fffu + ((u >> 16) & 1u);
    return (ushort)(r >> 16);
}

// ---------------- per-type linear + fused edge-mask scatter ----------------
// grid (512, 3): bx&1 = k-half (128 cols), bx>>1 = 32-row block. block 256.
// Blocks with by==0 additionally scatter the edge masks (512*256 = 131072 = 2*NE threads).
__global__ void __launch_bounds__(256) k_feat(const float* __restrict__ nf,
                                              const float* __restrict__ fc,
                                              const int* __restrict__ edges,
                                              float* __restrict__ msrc, float* __restrict__ mdst,
                                              float* __restrict__ feat) {
    __shared__ float sFC[64][132];        // fc[i][k-half] f32, padded
    __shared__ float sHT[64][36];         // transposed hs: [i][r] f32
    int t = threadIdx.x;
    int tt = blockIdx.y;
    if (tt == 0) {                        // fused scatter: e in [0, 2*NE)
        int e = blockIdx.x * 256 + t;
        if (e < NE) msrc[edges[e]] = 1.0f;
        else        mdst[edges[e]] = 1.0f;
    }
    int kh = blockIdx.x & 1;
    int r0 = (blockIdx.x >> 1) * 32;
    {   // load fc half-plane: 64 x 128 f32
        const float* fcp = fc + tt * 16384 + kh * 128;
        #pragma unroll
        for (int i = 0; i < 8; ++i) {
            int f4 = t + 256 * i;
            int row = f4 >> 5, c4 = f4 & 31;
            *(float4*)&sFC[row][c4 * 4] = *(const float4*)(fcp + row * 256 + c4 * 4);
        }
    }
    {   // load 32 rows x 64 inputs, transpose into sHT
        #pragma unroll
        for (int i = 0; i < 2; ++i) {
            int f4 = t + 256 * i;
            int r = f4 >> 4, c4 = f4 & 15;
            float4 v = *(const float4*)(nf + (size_t)(r0 + r) * 192 + tt * 64 + c4 * 4);
            sHT[c4 * 4 + 0][r] = v.x;
            sHT[c4 * 4 + 1][r] = v.y;
            sHT[c4 * 4 + 2][r] = v.z;
            sHT[c4 * 4 + 3][r] = v.w;
        }
    }
    __syncthreads();
    int rg = t >> 5;        // rows rg*4..+4
    int kg = t & 31;        // cols kg*4..+4 (of this 128 half)
    float acc[4][4];
    #pragma unroll
    for (int a = 0; a < 4; ++a)
        #pragma unroll
        for (int b = 0; b < 4; ++b) acc[a][b] = 0.f;
    #pragma unroll 4
    for (int i = 0; i < 64; ++i) {
        float4 hv = *(const float4*)&sHT[i][rg * 4];
        float4 fv = *(const float4*)&sFC[i][kg * 4];
        const float* fp = (const float*)&fv;
        #pragma unroll
        for (int b = 0; b < 4; ++b) {
            acc[0][b] += hv.x * fp[b];
            acc[1][b] += hv.y * fp[b];
            acc[2][b] += hv.z * fp[b];
            acc[3][b] += hv.w * fp[b];
        }
    }
    #pragma unroll
    for (int a = 0; a < 4; ++a) {
        int b = r0 + rg * 4 + a;
        int c = b >> 10, n = b & 1023;
        float4 vv = {acc[a][0], acc[a][1], acc[a][2], acc[a][3]};
        *(float4*)(feat + (size_t)c * 786432 + (size_t)tt * 262144 + n * 256 + kh * 128 + kg * 4) = vv;
    }
}

// ---------------- fused remap + transpose: feat -> fdt (bf16, masked) + attention partials ----------------
// grid (16 u-tiles, 3 t2, 8 c), block 256.  thread t: nl = t>>2 (node 0..63), q = t&3 (= h).
__global__ void __launch_bounds__(256) k_rt(const float* __restrict__ feat,
                        const float* __restrict__ attn_src, const float* __restrict__ attn_dst,
                        const float* __restrict__ msrc, const float* __restrict__ mdst,
                        ushort* __restrict__ fdt, float* __restrict__ a_src, float* __restrict__ a_dst) {
    __shared__ ushort T[22560];           // 256 rows x 88 + skew, 45.1 KB
    int u0 = blockIdx.x * 64;
    int t2 = blockIdx.y;
    int c  = blockIdx.z;
    int t = threadIdx.x;
    int nl = t >> 2, q = t & 3;
    int b = (c << 10) + u0 + nl;
    float md = mdst[b], ms = msrc[b];
    const float* fp  = feat + (size_t)c * 786432 + (size_t)(u0 + nl) * 768 + t2 * 256 + q * 64;
    const float* wsp = attn_src + q * 192 + t2 * 64;
    const float* wdp = attn_dst + q * 192 + t2 * 64;
    float ssum = 0.f, dsum = 0.f;
    #pragma unroll
    for (int i4 = 0; i4 < 16; ++i4) {
        float4 v = *(const float4*)(fp + i4 * 4);
        const float* vv = (const float*)&v;
        #pragma unroll
        for (int k = 0; k < 4; ++k) {
            int f = i4 * 4 + k;
            ssum += vv[k] * wsp[f];
            dsum += vv[k] * wdp[f];
            T[(q * 64 + f) * 88 + q * 16 + nl] = f2bfu(vv[k] * md);
        }
    }
    atomicAdd(&a_src[(b << 2) + q], ssum * ms);
    atomicAdd(&a_dst[(b << 2) + q], dsum * md);
    __syncthreads();
    // phase 2: one fdt row (128 B) per thread.
    int h2 = t >> 6, j = t & 63;
    const ushort* row = &T[(h2 * 64 + j) * 88 + h2 * 16];
    ushort* dst = fdt + (size_t)((c * 4 + h2) * 192 + t2 * 64 + j) * 1024 + u0;
    #pragma unroll
    for (int i = 0; i < 8; ++i)
        *(uint4*)(dst + i * 8) = *(const uint4*)(row + i * 8);
}

// ---------------- attention + softmax over c ----------------
// grid (1024 v, 2 u-chunks), block 256; thread handles u0 = chunk*512 + t and u1 = u0 + 256.
// Dense lane mapping for all loads and a_out stores. Abuf (bf16) is staged through a
// 32x520 LDS tile, then drained with 8 dense uint4 stores/thread: global store
// instructions per thread drop 80 -> 24 (same bytes). 3-pass recompute softmax.
__global__ void __launch_bounds__(256) k_att(const float* __restrict__ a_src,
                                             const float* __restrict__ a_dst,
                                             float* __restrict__ a_out, ushort* __restrict__ Abuf) {
    __shared__ float sAS[32];
    __shared__ ushort T2[32 * 520];       // 33.3 KB: [ch 32][u-local 512 + 8 pad]
    int v = blockIdx.x;
    int t = threadIdx.x;
    if (t < 32) sAS[t] = a_src[((t >> 2) * 1024 + v) * 4 + (t & 3)];
    __syncthreads();
    int u0 = blockIdx.y * 512 + t;
    int u1 = u0 + 256;

    // ---- pass 1: raw max over c (leaky/clip applied once afterwards) ----
    float mx0[4], mx1[4];
    #pragma unroll
    for (int h = 0; h < 4; ++h) { mx0[h] = -1e30f; mx1[h] = -1e30f; }
    #pragma unroll
    for (int c = 0; c < 8; ++c) {
        float4 d0 = *(const float4*)(a_dst + ((c << 10) + u0) * 4);
        float4 d1 = *(const float4*)(a_dst + ((c << 10) + u1) * 4);
        const float* dp0 = (const float*)&d0;
        const float* dp1 = (const float*)&d1;
        #pragma unroll
        for (int h = 0; h < 4; ++h) {
            float as = sAS[c * 4 + h];
            mx0[h] = fmaxf(mx0[h], as + dp0[h]);
            mx1[h] = fmaxf(mx1[h], as + dp1[h]);
        }
    }
    #pragma unroll
    for (int h = 0; h < 4; ++h) {
        float x = mx0[h];
        x = (x >= 0.f) ? x : NEG_SLOPE * x;
        mx0[h] = fminf(fmaxf(x, -1e9f), 1e9f);
        float y = mx1[h];
        y = (y >= 0.f) ? y : NEG_SLOPE * y;
        mx1[h] = fminf(fmaxf(y, -1e9f), 1e9f);
    }

    // ---- pass 2: recompute logits, accumulate exp sums ----
    float s0[4] = {0.f, 0.f, 0.f, 0.f}, s1[4] = {0.f, 0.f, 0.f, 0.f};
    #pragma unroll
    for (int c = 0; c < 8; ++c) {
        float4 d0 = *(const float4*)(a_dst + ((c << 10) + u0) * 4);
        float4 d1 = *(const float4*)(a_dst + ((c << 10) + u1) * 4);
        const float* dp0 = (const float*)&d0;
        const float* dp1 = (const float*)&d1;
        #pragma unroll
        for (int h = 0; h < 4; ++h) {
            float as = sAS[c * 4 + h];
            float x = as + dp0[h];
            x = (x >= 0.f) ? x : NEG_SLOPE * x;
            x = fminf(fmaxf(x, -1e9f), 1e9f);
            s0[h] += __expf(x - mx0[h]);
            float y = as + dp1[h];
            y = (y >= 0.f) ? y : NEG_SLOPE * y;
            y = fminf(fmaxf(y, -1e9f), 1e9f);
            s1[h] += __expf(y - mx1[h]);
        }
    }
    float r0[4], r1[4];
    #pragma unroll
    for (int h = 0; h < 4; ++h) { r0[h] = 1.f / s0[h]; r1[h] = 1.f / s1[h]; }

    // ---- pass 3: recompute, normalize, write a_out (f32) + stage Abuf into LDS ----
    #pragma unroll
    for (int c = 0; c < 8; ++c) {
        float4 d0 = *(const float4*)(a_dst + ((c << 10) + u0) * 4);
        float4 d1 = *(const float4*)(a_dst + ((c << 10) + u1) * 4);
        const float* dp0 = (const float*)&d0;
        const float* dp1 = (const float*)&d1;
        float w0[4], w1[4];
        #pragma unroll
        for (int h = 0; h < 4; ++h) {
            float as = sAS[c * 4 + h];
            float x = as + dp0[h];
            x = (x >= 0.f) ? x : NEG_SLOPE * x;
            x = fminf(fmaxf(x, -1e9f), 1e9f);
            w0[h] = __expf(x - mx0[h]) * r0[h];
            float y = as + dp1[h];
            y = (y >= 0.f) ? y : NEG_SLOPE * y;
            y = fminf(fmaxf(y, -1e9f), 1e9f);
            w1[h] = __expf(y - mx1[h]) * r1[h];
        }
        float* ao0 = a_out + ((size_t)((c << 10) + v) * 1024 + u0) * 4;
        float* ao1 = a_out + ((size_t)((c << 10) + v) * 1024 + u1) * 4;
        *(float4*)ao0 = *(const float4*)w0;
        *(float4*)ao1 = *(const float4*)w1;
        #pragma unroll
        for (int h = 0; h < 4; ++h) {
            T2[(c * 4 + h) * 520 + t]       = f2bfu(w0[h]);
            T2[(c * 4 + h) * 520 + t + 256] = f2bfu(w1[h]);
        }
    }
    __syncthreads();
    // ---- drain LDS tile to Abuf: 2048 uint4s, 8 per thread, fully dense ----
    #pragma unroll
    for (int i = 0; i < 8; ++i) {
        int id = t + 256 * i;             // 0..2047
        int row = id >> 6;                // ch plane 0..31
        int c16 = id & 63;                // 16B chunk within the 512-u span
        uint4 vv = *(const uint4*)&T2[row * 520 + c16 * 8];
        *(uint4*)(Abuf + (size_t)(row * 1024 + v) * 1024 + blockIdx.y * 512 + c16 * 8) = vv;
    }
}

// ---------------- GEMM per (c,h): M[v][j] = sum_u A[v][u] * fdt[j][u] ----------------
// grid (8 v-tiles, 32 ch) = 256 blocks, block 512 (8 waves). BM=128, BN=192, BK=64.
// Wave grid 2m x 4n: wave covers 64 rows (4x16) x 48 cols (3x16).
__global__ void __launch_bounds__(512) k_gemm(const ushort* __restrict__ A,
                                              const ushort* __restrict__ B,
                                              float* __restrict__ Mout) {
    __shared__ ushort sA[128 * 72];
    __shared__ ushort sB[192 * 72];
    int ch = blockIdx.y;
    int v0 = blockIdx.x * 128;
    int t = threadIdx.x;
    const ushort* pA = A + (size_t)ch * (1024 * 1024) + (size_t)v0 * 1024;
    const ushort* pB = B + (size_t)ch * (192 * 1024);
    int wid = t >> 6, lane = t & 63;
    int wm = (wid >> 2) * 64, wn = (wid & 3) * 48;
    int lm = lane & 15, lq = lane >> 4;
    f32x4 acc[4][3];
    #pragma unroll
    for (int i = 0; i < 4; ++i)
        #pragma unroll
        for (int j = 0; j < 3; ++j)
            acc[i][j] = (f32x4){0.f, 0.f, 0.f, 0.f};
    for (int kk = 0; kk < 1024; kk += 64) {
        #pragma unroll
        for (int i = 0; i < 2; ++i) {
            int cid = t + 512 * i;
            int r = cid >> 3, kc = cid & 7;
            uint4 vv = *(const uint4*)(pA + (size_t)r * 1024 + kk + kc * 8);
            *(uint4*)&sA[r * 72 + kc * 8] = vv;
        }
        #pragma unroll
        for (int i = 0; i < 3; ++i) {
            int cid = t + 512 * i;
            int r = cid >> 3, kc = cid & 7;
            uint4 vv = *(const uint4*)(pB + (size_t)r * 1024 + kk + kc * 8);
            *(uint4*)&sB[r * 72 + kc * 8] = vv;
        }
        __syncthreads();
        #pragma unroll
        for (int ks = 0; ks < 64; ks += 32) {
            bf16x8 af[4], bg[3];
            #pragma unroll
            for (int i = 0; i < 4; ++i)
                af[i] = *(const bf16x8*)&sA[(wm + i * 16 + lm) * 72 + ks + lq * 8];
            #pragma unroll
            for (int j = 0; j < 3; ++j)
                bg[j] = *(const bf16x8*)&sB[(wn + j * 16 + lm) * 72 + ks + lq * 8];
            #pragma unroll
            for (int i = 0; i < 4; ++i)
                #pragma unroll
                for (int j = 0; j < 3; ++j)
                    acc[i][j] = __builtin_amdgcn_mfma_f32_16x16x32_bf16(af[i], bg[j], acc[i][j], 0, 0, 0);
        }
        __syncthreads();
    }
    float* pM = Mout + (size_t)ch * 196608 + (size_t)v0 * 192;
    #pragma unroll
    for (int i = 0; i < 4; ++i)
        #pragma unroll
        for (int r = 0; r < 4; ++r) {
            int row = wm + i * 16 + lq * 4 + r;
            #pragma unroll
            for (int j = 0; j < 3; ++j)
                pM[(size_t)row * 192 + wn + j * 16 + lm] = acc[i][j][r];
        }
}

// ---------------- epilogue: outs[c][v][tf] = sum_h relu(M[ch][v][tf]) (f32) ----------------
__global__ void k_out(const float* __restrict__ Mm, float* __restrict__ outp) {
    int b = blockIdx.x;
    int c = b >> 10, v = b & 1023;
    int tf = threadIdx.x;
    float s = 0.f;
    #pragma unroll
    for (int h = 0; h < 4; ++h) {
        float x = Mm[(size_t)(c * 4 + h) * 196608 + (size_t)v * 192 + tf];
        s += fmaxf(x, 0.f);
    }
    outp[(size_t)b * 192 + tf] = s;
}

extern "C" void kernel_launch(void* const* d_in, const int* in_sizes, int n_in,
                              void* d_out, int out_size, void* d_ws, size_t ws_size,
                              hipStream_t stream) {
    const int*   edges  = (const int*)d_in[0];
    const float* nf     = (const float*)d_in[1];
    const float* fc     = (const float*)d_in[2];
    const float* asrc_w = (const float*)d_in[3];
    const float* adst_w = (const float*)d_in[4];
    float* outp  = (float*)d_out;
    float* a_out = outp + 1572864;     // outs (1,572,864 f32) then a (33,554,432 f32)

    char* ws = (char*)d_ws;
    float*  msrc  = (float*)(ws + 0);            // 32 KB
    float*  mdst  = (float*)(ws + 32768);        // 32 KB
    float*  a_src = (float*)(ws + 65536);        // 128 KB (atomic-accumulated)
    float*  a_dst = (float*)(ws + 196608);       // 128 KB (atomic-accumulated)
    ushort* fdt   = (ushort*)(ws + 327680);      // 12.58 MB bf16
    float*  feat  = (float*)(ws + 12910592);     // 25.17 MB f32 (aliased with Mm)
    float*  Mm    = feat;                        // feat dead after k_rt
    ushort* Abuf  = (ushort*)(ws + 38076416);    // 67.1 MB bf16

    hipMemsetAsync(msrc, 0, 327680, stream);     // zero masks + a_src + a_dst
    k_feat<<<dim3(512, 3), dim3(256), 0, stream>>>(nf, fc, edges, msrc, mdst, feat);
    k_rt<<<dim3(16, 3, 8), dim3(256), 0, stream>>>(feat, asrc_w, adst_w, msrc, mdst, fdt, a_src, a_dst);
    k_att<<<dim3(1024, 2), dim3(256), 0, stream>>>(a_src, a_dst, a_out, Abuf);
    k_gemm<<<dim3(8, 32), dim3(512), 0, stream>>>(Abuf, fdt, Mm);
    k_out<<<dim3(8192), dim3(192), 0, stream>>>(Mm, outp);
}